// Round 10
// baseline (356.802 us; speedup 1.0000x reference)
//
#include <hip/hip_runtime.h>
#include <hip/hip_bf16.h>
#include <cstdint>
#include <cstddef>

// ActorHead fused pipeline, bf16 MFMA throughout.
//   K1 k_qkv : LDS-tiled GEMM-BT [4096x1536x512], 128x64 tiles (768 wgs)
//              -> Qb row-major (scaled), Kp/Vp MFMA-fragment-packed
//   K2 k_attn: split-K(S=8) flash attention, S^T ordering, P register-resident.
//              32 rows/wave: one set of K/V frags serves two 16-row MFMA blocks
//              (halves chunk count + K/V VMEM — round-9 showed the VMEM path, not
//              wave supply, is the limiter: occupancy pinned ~12 waves/CU at S=4 and S=8).
//              VGPR ~160 via __launch_bounds__(256,3) = 3 waves/SIMD = observed residency.
//   K2b k_comb: merge splits, influence, valid
//   K3 k_fold: fold out_w over heads; K4 k_out: [4096x128x512] GEMM (256 wgs)
// d_out = topic[4096*128] fp32 ++ influence[4096] fp32

typedef __attribute__((ext_vector_type(8))) short bf16x8;
typedef __attribute__((ext_vector_type(4))) short bf16x4;
typedef __attribute__((ext_vector_type(4))) float f32x4;

#define MFMA32(a, b, c) __builtin_amdgcn_mfma_f32_16x16x32_bf16((a), (b), (c), 0, 0, 0)
// K=16 bf16 MFMA: gfx90a-era "_1k" spelling; maps to v_mfma_f32_16x16x16_bf16 (valid gfx950).
#define MFMA16(a, b, c) __builtin_amdgcn_mfma_f32_16x16x16bf16_1k((a), (b), (c), 0, 0, 0)

static __device__ __forceinline__ short f2b(float x) {
  union { float f; unsigned u; } v; v.f = x;
  unsigned r = v.u + 0x7fffu + ((v.u >> 16) & 1u);  // RNE to bf16
  return (short)(r >> 16);
}

// ---------------- K1: QKV projection (LDS-tiled 128x64, packed epilogue) ----------------
__global__ __launch_bounds__(256) void k_qkv(
    const float* __restrict__ a, const float* __restrict__ kv,
    const float* __restrict__ w, const float* __restrict__ bias,
    short* __restrict__ Qb, short* __restrict__ Kp, short* __restrict__ Vp)
{
  __shared__ short As[128 * 40];
  __shared__ short Bs[64 * 40];
  const int blk = blockIdx.x;
  const int bm = blk % 32, bn = blk / 32;  // bn 0..23; consecutive blocks share w-slice
  const int m0 = bm * 128, n0 = bn * 64;
  const float* __restrict__ Ain = (bn < 8) ? a : kv;
  const int tid = threadIdx.x;
  const int lane = tid & 63, wvi = tid >> 6;
  const int wm = (wvi >> 1) * 64, wn = (wvi & 1) * 32;
  const int c = lane & 15, g = lane >> 4;
  const int srA = tid >> 1, scA = (tid & 1) * 16;
  const int srB = tid >> 2, scB = (tid & 3) * 8;

  f32x4 acc[4][2];
#pragma unroll
  for (int i = 0; i < 4; ++i)
#pragma unroll
    for (int j = 0; j < 2; ++j) acc[i][j] = (f32x4)0.f;

  for (int k0 = 0; k0 < 512; k0 += 32) {
    const float* ap = Ain + (size_t)(m0 + srA) * 512 + k0 + scA;
#pragma unroll
    for (int j = 0; j < 4; ++j) {
      f32x4 av = *(const f32x4*)(ap + 4 * j);
      bf16x4 as;
      as.x = f2b(av.x); as.y = f2b(av.y); as.z = f2b(av.z); as.w = f2b(av.w);
      *(bf16x4*)(&As[srA * 40 + scA + 4 * j]) = as;
    }
    const float* bp = w + (size_t)(n0 + srB) * 512 + k0 + scB;
#pragma unroll
    for (int j = 0; j < 2; ++j) {
      f32x4 bv = *(const f32x4*)(bp + 4 * j);
      bf16x4 bs;
      bs.x = f2b(bv.x); bs.y = f2b(bv.y); bs.z = f2b(bv.z); bs.w = f2b(bv.w);
      *(bf16x4*)(&Bs[srB * 40 + scB + 4 * j]) = bs;
    }
    __syncthreads();
    bf16x8 af[4], bfg[2];
#pragma unroll
    for (int t = 0; t < 4; ++t)
      af[t] = *(const bf16x8*)(&As[(wm + t * 16 + c) * 40 + g * 8]);
#pragma unroll
    for (int t = 0; t < 2; ++t)
      bfg[t] = *(const bf16x8*)(&Bs[(wn + t * 16 + c) * 40 + g * 8]);
#pragma unroll
    for (int rt = 0; rt < 4; ++rt)
#pragma unroll
      for (int ct = 0; ct < 2; ++ct)
        acc[rt][ct] = MFMA32(af[rt], bfg[ct], acc[rt][ct]);
    __syncthreads();
  }

#pragma unroll
  for (int ct = 0; ct < 2; ++ct) {
    const int col = n0 + wn + ct * 16 + c;
    const float bj = bias[col];
#pragma unroll
    for (int rt = 0; rt < 4; ++rt) {
      const int row = m0 + wm + rt * 16 + g * 4;  // row&15 = g*4
      const int mc = row >> 4;
      if (col < 512) {
#pragma unroll
        for (int r = 0; r < 4; ++r)
          Qb[(size_t)(row + r) * 512 + col] = f2b((acc[rt][ct][r] + bj) * 0.08838834764831843f);
      } else if (col < 1024) {
        const int colK = col - 512;
        const int h = colK >> 7, dk = colK & 127;
        const int ks = dk >> 5, gk = (dk >> 3) & 3, j = dk & 7;
        short* base = Kp + (size_t)((((h * 256 + mc) * 4 + ks) * 64) + gk * 16 + g * 4) * 8 + j;
#pragma unroll
        for (int r = 0; r < 4; ++r) base[r * 8] = f2b(acc[rt][ct][r] + bj);
      } else {
        const int colV = col - 1024;
        const int h = colV >> 7, db = (colV & 127) >> 4, cv = colV & 15;
        bf16x4 pk;
#pragma unroll
        for (int r = 0; r < 4; ++r) pk[r] = f2b(acc[rt][ct][r] + bj);
        *(bf16x4*)(Vp + (size_t)((((h * 256 + mc) * 8 + db) * 64) + g * 16 + cv) * 4) = pk;
      }
    }
  }
}

// ---------------- K2: split-K flash attention (32 rows/wave, K/V amortized 2x) -----------
__global__ __launch_bounds__(256, 3) void k_attn(
    const short* __restrict__ Qb, const short* __restrict__ Kp,
    const short* __restrict__ Vp, const float* __restrict__ wgt,
    const int* __restrict__ msk, const int S,
    short* __restrict__ Opart, float* __restrict__ lpart,
    float* __restrict__ cipart, float* __restrict__ lbpart)
{
  const int bx = blockIdx.x;
  const int rb = bx & 127, sp = bx >> 7;
  const int n0 = rb * 32;
  const int mlen = 4096 / S;
  const int mc0 = (sp * mlen) >> 4;
  const int nch = mlen >> 4;
  const int tid = threadIdx.x;
  const int lane = tid & 63, h = tid >> 6;
  const int c = lane & 15, g = lane >> 4;

  bf16x8 qf[2][4];
#pragma unroll
  for (int nb = 0; nb < 2; ++nb)
#pragma unroll
    for (int ks = 0; ks < 4; ++ks)
      qf[nb][ks] = *(const bf16x8*)(Qb + (size_t)(n0 + nb * 16 + c) * 512 + h * 128 + ks * 32 + g * 8);

  f32x4 O[2][8];
#pragma unroll
  for (int nb = 0; nb < 2; ++nb)
#pragma unroll
    for (int db = 0; db < 8; ++db) O[nb][db] = (f32x4)0.f;
  float lh[2] = {0.f, 0.f}, lb2[2] = {0.f, 0.f}, ci[2] = {0.f, 0.f};

  const short* Kw = Kp + (size_t)h * 524288 + (size_t)lane * 8 + (size_t)mc0 * 2048;
  const short* Vw = Vp + (size_t)h * 524288 + (size_t)lane * 4 + (size_t)mc0 * 2048;
  const int* mp = msk + (size_t)(n0 + c) * 4096 + g * 4 + (size_t)mc0 * 16;
  const float* wp = wgt + (size_t)(n0 + c) * 4096 + g * 4 + (size_t)mc0 * 16;
  const int nboff = 16 * 4096;  // second 16-row half

  // prefetch chunk-0 mask/weight for both row halves
  int4 mk0 = *(const int4*)(mp);
  f32x4 wv0 = *(const f32x4*)(wp);
  int4 mk1 = *(const int4*)(mp + nboff);
  f32x4 wv1 = *(const f32x4*)(wp + nboff);

  for (int t = 0; t < nch; ++t) {
    // 1) issue shared K and V loads (serve both row halves)
    bf16x8 kf[4];
#pragma unroll
    for (int ks = 0; ks < 4; ++ks)
      kf[ks] = *(const bf16x8*)(Kw + t * 2048 + ks * 512);
    bf16x4 vf[8];
#pragma unroll
    for (int db = 0; db < 8; ++db)
      vf[db] = *(const bf16x4*)(Vw + t * 2048 + db * 256);

    // 2) e from current mask regs (kills them early -> lower peak VGPR)
    const float ea0 = mk0.x ? __expf(wv0.x) : 0.f;
    const float ea1 = mk0.y ? __expf(wv0.y) : 0.f;
    const float ea2 = mk0.z ? __expf(wv0.z) : 0.f;
    const float ea3 = mk0.w ? __expf(wv0.w) : 0.f;
    const float eb0 = mk1.x ? __expf(wv1.x) : 0.f;
    const float eb1 = mk1.y ? __expf(wv1.y) : 0.f;
    const float eb2 = mk1.z ? __expf(wv1.z) : 0.f;
    const float eb3 = mk1.w ? __expf(wv1.w) : 0.f;

    // 3) issue next chunk's mask/weight
    const int tn = (t + 1 < nch) ? (t + 1) : t;
    mk0 = *(const int4*)(mp + tn * 16);
    wv0 = *(const f32x4*)(wp + tn * 16);
    mk1 = *(const int4*)(mp + nboff + tn * 16);
    wv1 = *(const f32x4*)(wp + nboff + tn * 16);

    // 4) QK for both row halves (kf shared)
    f32x4 Sv0 = (f32x4)0.f, Sv1 = (f32x4)0.f;
#pragma unroll
    for (int ks = 0; ks < 4; ++ks) {
      Sv0 = MFMA32(kf[ks], qf[0][ks], Sv0);
      Sv1 = MFMA32(kf[ks], qf[1][ks], Sv1);
    }

    // 5) p = exp(qk)*e, accumulate, pack
    const float p00 = __expf(Sv0[0]) * ea0, p01 = __expf(Sv0[1]) * ea1;
    const float p02 = __expf(Sv0[2]) * ea2, p03 = __expf(Sv0[3]) * ea3;
    const float p10 = __expf(Sv1[0]) * eb0, p11 = __expf(Sv1[1]) * eb1;
    const float p12 = __expf(Sv1[2]) * eb2, p13 = __expf(Sv1[3]) * eb3;
    lh[0] += (p00 + p01) + (p02 + p03);
    lh[1] += (p10 + p11) + (p12 + p13);
    lb2[0] += (ea0 + ea1) + (ea2 + ea3);
    lb2[1] += (eb0 + eb1) + (eb2 + eb3);
    ci[0] += (p00 * ea0 + p01 * ea1) + (p02 * ea2 + p03 * ea3);
    ci[1] += (p10 * eb0 + p11 * eb1) + (p12 * eb2 + p13 * eb3);
    bf16x4 pa0, pa1;
    pa0[0] = f2b(p00); pa0[1] = f2b(p01); pa0[2] = f2b(p02); pa0[3] = f2b(p03);
    pa1[0] = f2b(p10); pa1[1] = f2b(p11); pa1[2] = f2b(p12); pa1[3] = f2b(p13);

    // 6) PV for both row halves (vf shared)
#pragma unroll
    for (int db = 0; db < 8; ++db) {
      O[0][db] = MFMA16(pa0, vf[db], O[0][db]);
      O[1][db] = MFMA16(pa1, vf[db], O[1][db]);
    }
  }

  // reduce over g-groups (lanes ^16, ^32 share actor n=c)
#pragma unroll
  for (int nb = 0; nb < 2; ++nb) {
    lh[nb] += __shfl_xor(lh[nb], 16, 64); lh[nb] += __shfl_xor(lh[nb], 32, 64);
    lb2[nb] += __shfl_xor(lb2[nb], 16, 64); lb2[nb] += __shfl_xor(lb2[nb], 32, 64);
    ci[nb] += __shfl_xor(ci[nb], 16, 64); ci[nb] += __shfl_xor(ci[nb], 32, 64);
  }

#pragma unroll
  for (int nb = 0; nb < 2; ++nb) {
    float inv[4];
#pragma unroll
    for (int r = 0; r < 4; ++r)
      inv[r] = 1.f / fmaxf(__shfl(lh[nb], 4 * g + r, 64), 1e-30f);
#pragma unroll
    for (int db = 0; db < 8; ++db)
#pragma unroll
      for (int r = 0; r < 4; ++r)
        Opart[(size_t)sp * (4096 * 512) + (size_t)(n0 + nb * 16 + g * 4 + r) * 512 +
              h * 128 + db * 16 + c] = f2b(O[nb][db][r] * inv[r]);
  }

  if (g == 0) {
#pragma unroll
    for (int nb = 0; nb < 2; ++nb) {
      const int row = n0 + nb * 16 + c;
      lpart[((size_t)sp * 4 + h) * 4096 + row] = lh[nb];
      cipart[((size_t)sp * 4 + h) * 4096 + row] = ci[nb];
      if (h == 0) lbpart[(size_t)sp * 4096 + row] = lb2[nb];
    }
  }
}

// ---------------- K2b: combine splits ----------------
__global__ __launch_bounds__(256) void k_comb(
    const short* __restrict__ Opart, const float* __restrict__ lpart,
    const float* __restrict__ cipart, const float* __restrict__ lbpart,
    const int S, short* __restrict__ ctxb, float* __restrict__ validw,
    float* __restrict__ infl)
{
  const int tid = threadIdx.x;
  const int rloc = tid >> 5, cseg = tid & 31;
  const int row = blockIdx.x * 8 + rloc;
  const int col0 = cseg * 16;
  const int h = col0 >> 7;

  float l[4], ciS[4], lb = 0.f;
#pragma unroll
  for (int hh = 0; hh < 4; ++hh) { l[hh] = 0.f; ciS[hh] = 0.f; }
  for (int s = 0; s < S; ++s) {
#pragma unroll
    for (int hh = 0; hh < 4; ++hh) {
      l[hh]   += lpart[((size_t)s * 4 + hh) * 4096 + row];
      ciS[hh] += cipart[((size_t)s * 4 + hh) * 4096 + row];
    }
    lb += lbpart[(size_t)s * 4096 + row];
  }

  float acc[16];
#pragma unroll
  for (int j = 0; j < 16; ++j) acc[j] = 0.f;
  const float linv = 1.f / fmaxf(l[h], 1e-30f);
  for (int s = 0; s < S; ++s) {
    const float w_s = lpart[((size_t)s * 4 + h) * 4096 + row] * linv;
    const bf16x8 o0 = *(const bf16x8*)(Opart + (size_t)s * (4096 * 512) + (size_t)row * 512 + col0);
    const bf16x8 o1 = *(const bf16x8*)(Opart + (size_t)s * (4096 * 512) + (size_t)row * 512 + col0 + 8);
#pragma unroll
    for (int j = 0; j < 8; ++j) {
      union { unsigned u; float f; } v0, v1;
      v0.u = ((unsigned)(unsigned short)o0[j]) << 16;
      v1.u = ((unsigned)(unsigned short)o1[j]) << 16;
      acc[j]     += w_s * v0.f;
      acc[8 + j] += w_s * v1.f;
    }
  }
  bf16x8 c0, c1;
#pragma unroll
  for (int j = 0; j < 8; ++j) { c0[j] = f2b(acc[j]); c1[j] = f2b(acc[8 + j]); }
  *(bf16x8*)(ctxb + (size_t)row * 512 + col0) = c0;
  *(bf16x8*)(ctxb + (size_t)row * 512 + col0 + 8) = c1;

  if (cseg == 0) {
    validw[row] = (lb > 0.f) ? 1.f : 0.f;
    float s_ = 0.f;
#pragma unroll
    for (int hh = 0; hh < 4; ++hh) s_ += ciS[hh] / fmaxf(l[hh], 1e-30f);
    infl[row] = (lb > 0.f) ? s_ / (4.f * lb) : 0.f;
  }
}

// ---------------- K3: fold out_w over heads ----------------
__global__ void k_fold(const float* __restrict__ ow, const float* __restrict__ ob,
                       short* __restrict__ Wf, float* __restrict__ bfo)
{
  const int idx = blockIdx.x * 256 + threadIdx.x;
  if (idx < 128 * 512) {
    const int dk = idx >> 9, d = idx & 511;
    const float s = 0.25f * (ow[(size_t)dk * 512 + d] + ow[(size_t)(dk + 128) * 512 + d] +
                             ow[(size_t)(dk + 256) * 512 + d] + ow[(size_t)(dk + 384) * 512 + d]);
    Wf[(size_t)dk * 512 + d] = f2b(s);
  }
  if (idx < 128) bfo[idx] = 0.25f * (ob[idx] + ob[idx + 128] + ob[idx + 256] + ob[idx + 384]);
}

// ---------------- K4: topic = ctx @ Wfold^T + bfold (256 wgs, direct frags) ----------------
__global__ __launch_bounds__(256) void k_out(
    const short* __restrict__ ctxb, const short* __restrict__ Wf,
    const float* __restrict__ bfo, const float* __restrict__ validw,
    float* __restrict__ topic)
{
  const int tid = threadIdx.x;
  const int lane = tid & 63, wvi = tid >> 6;
  const int m0 = blockIdx.x * 16;
  const int c = lane & 15, g = lane >> 4;

  f32x4 acc[2];
  acc[0] = (f32x4)0.f; acc[1] = (f32x4)0.f;

  for (int k0 = 0; k0 < 512; k0 += 32) {
    const bf16x8 af = *(const bf16x8*)(ctxb + (size_t)(m0 + c) * 512 + k0 + g * 8);
#pragma unroll
    for (int dbl = 0; dbl < 2; ++dbl) {
      const bf16x8 bfr = *(const bf16x8*)(Wf + (size_t)(wvi * 32 + dbl * 16 + c) * 512 + k0 + g * 8);
      acc[dbl] = MFMA32(af, bfr, acc[dbl]);
    }
  }

#pragma unroll
  for (int r = 0; r < 4; ++r) {
    const int row = m0 + g * 4 + r;
    const float va = validw[row];
#pragma unroll
    for (int dbl = 0; dbl < 2; ++dbl) {
      const int col = wvi * 32 + dbl * 16 + c;
      const float vl = (va > 0.5f) ? (acc[dbl][r] + bfo[col]) : 0.f;
      topic[(size_t)row * 128 + col] = vl;
    }
  }
}

extern "C" void kernel_launch(void* const* d_in, const int* in_sizes, int n_in,
                              void* d_out, int out_size, void* d_ws, size_t ws_size,
                              hipStream_t stream) {
  const float* a_z  = (const float*)d_in[0];
  const float* bv_z = (const float*)d_in[1];
  const int*   mask = (const int*)d_in[2];
  const float* wgt  = (const float*)d_in[3];
  const float* ipw  = (const float*)d_in[4];
  const float* ipb  = (const float*)d_in[5];
  const float* ow   = (const float*)d_in[6];
  const float* ob   = (const float*)d_in[7];
  float* topic = (float*)d_out;              // [4096 x 128]
  float* infl  = (float*)d_out + 4096 * 128; // [4096]

  const size_t MB = (size_t)1 << 20;
  char* ws = (char*)d_ws;
  short* Qb     = (short*)(ws);                    // 4 MB
  short* Kp     = (short*)(ws + 4 * MB);           // 4 MB packed K frags
  short* Vp     = (short*)(ws + 8 * MB);           // 4 MB packed V frags
  short* ctxb   = (short*)(ws + 12 * MB);          // 4 MB
  float* validw = (float*)(ws + 16 * MB);          // 16 KB
  short* Wf     = (short*)(ws + 16 * MB + (64 << 10));   // 128 KB
  float* bfo    = (float*)(ws + 16 * MB + (224 << 10));  // 512 B
  const size_t pbase0 = 16 * MB + (256 << 10);

  // per split: Opart 4MB + lpart 64KB + cipart 64KB + lbpart 16KB
  auto need = [&](int S) { return pbase0 + (size_t)S * (4 * MB + (144 << 10)); };
  int S = 8;
  while (S > 1 && need(S) > ws_size) S >>= 1;

  char* pbase = ws + pbase0;
  short* Opart  = (short*)(pbase);
  float* lpart  = (float*)(pbase + (size_t)S * 4 * MB);
  float* cipart = (float*)(pbase + (size_t)S * 4 * MB + ((size_t)S << 16));
  float* lbpart = (float*)(pbase + (size_t)S * 4 * MB + ((size_t)S << 17));

  k_qkv <<<768, 256, 0, stream>>>(a_z, bv_z, ipw, ipb, Qb, Kp, Vp);
  k_fold<<<256, 256, 0, stream>>>(ow, ob, Wf, bfo);
  k_attn<<<128 * S, 256, 0, stream>>>(Qb, Kp, Vp, wgt, mask, S, Opart, lpart, cipart, lbpart);
  k_comb<<<512, 256, 0, stream>>>(Opart, lpart, cipart, lbpart, S, ctxb, validw, infl);
  k_out <<<256, 256, 0, stream>>>(ctxb, Wf, bfo, validw, topic);
}